// Round 8
// baseline (175.363 us; speedup 1.0000x reference)
//
#include <hip/hip_runtime.h>
#include <cmath>

#define HDIM 1024
#define LSEQ 2048
#define VOCAB 50257
#define LOGIT_GRID 2048                    // exactly fills 256 CUs at 8 blocks/CU
#define LOGIT_WAVES (LOGIT_GRID * 4)       // 8192 waves

typedef float f4 __attribute__((ext_vector_type(4)));

__device__ __forceinline__ float wave_sum(float v) {
#pragma unroll
    for (int off = 32; off; off >>= 1) v += __shfl_down(v, off, 64);
    return v;
}

__device__ __forceinline__ void lse_combine(float& m, float& s, float m2, float s2) {
    float nm = fmaxf(m, m2);
    s = s * expf(m - nm) + s2 * expf(m2 - nm);
    m = nm;
}

// ---------------------------------------------------------------------------
// 1. h = tanh(W_ih @ x + b_ih + W_hh @ h0 + b_hh).  split-K, 2 waves/row.
__global__ void rnn_kernel(const int* __restrict__ tok,
                           const float* __restrict__ hidden,
                           const float* __restrict__ emb,
                           const float* __restrict__ W_ih,
                           const float* __restrict__ W_hh,
                           const float* __restrict__ b_ih,
                           const float* __restrict__ b_hh,
                           float* __restrict__ concat,
                           float* __restrict__ out_h) {
    __shared__ float sh[4];
    int t = threadIdx.x;
    int wave = t >> 6, lane = t & 63;
    int subrow = wave >> 1;
    int half   = wave & 1;
    int row = blockIdx.x * 2 + subrow;
    int d = row >> 10, i = row & 1023;
    int tk = tok[0];
    int off = half * 512 + lane * 8;
    const float* x  = emb + (size_t)tk * HDIM + off;
    const float* h0 = hidden + d * HDIM + off;
    const float* wi = W_ih + (size_t)d * HDIM * HDIM + (size_t)i * HDIM + off;
    const float* wh = W_hh + (size_t)d * HDIM * HDIM + (size_t)i * HDIM + off;

    float4 a0 = *(const float4*)(wi);
    float4 a1 = *(const float4*)(wi + 4);
    float4 b0 = *(const float4*)(x);
    float4 b1 = *(const float4*)(x + 4);
    float4 c0 = *(const float4*)(wh);
    float4 c1 = *(const float4*)(wh + 4);
    float4 e0 = *(const float4*)(h0);
    float4 e1 = *(const float4*)(h0 + 4);
    float acc = a0.x * b0.x + a0.y * b0.y + a0.z * b0.z + a0.w * b0.w
              + a1.x * b1.x + a1.y * b1.y + a1.z * b1.z + a1.w * b1.w
              + c0.x * e0.x + c0.y * e0.y + c0.z * e0.z + c0.w * e0.w
              + c1.x * e1.x + c1.y * e1.y + c1.z * e1.z + c1.w * e1.w;
    acc = wave_sum(acc);
    if (lane == 0) sh[wave] = acc;
    __syncthreads();
    if ((t & 127) == 0) {
        float hv = tanhf(sh[subrow * 2] + sh[subrow * 2 + 1]
                         + b_ih[d * HDIM + i] + b_hh[d * HDIM + i]);
        concat[d * 2048 + 1024 + i] = hv;
        out_h[d * HDIM + i] = hv;
    }
}

// ---------------------------------------------------------------------------
// 2. Flash-style fused attention partials.
__global__ void flash_attn_kernel(const float* __restrict__ enc,
                                  const float* __restrict__ concat,
                                  float* __restrict__ part,
                                  float* __restrict__ pm_a,
                                  float* __restrict__ ps_a) {
    __shared__ float e_sh[32];
    int b = blockIdx.x;
    int d = b >> 6, c = b & 63;
    int t = threadIdx.x, wave = t >> 6, lane = t & 63;
    int base = c * 32;
    const float* h = concat + d * 2048 + 1024;

    for (int r = 0; r < 8; ++r) {
        int ll = wave * 8 + r;
        const float* er = enc + (size_t)(base + ll) * HDIM;
        float acc = 0.f;
#pragma unroll
        for (int p = 0; p < 4; ++p) {
            int o = p * 256 + lane * 4;
            float4 a = *(const float4*)(er + o);
            float4 bb = *(const float4*)(h + o);
            acc += a.x * bb.x + a.y * bb.y + a.z * bb.z + a.w * bb.w;
        }
        acc = wave_sum(acc);
        if (lane == 0) e_sh[ll] = acc;
    }
    __syncthreads();

    float m_c = -1e30f;
#pragma unroll
    for (int l = 0; l < 32; ++l) m_c = fmaxf(m_c, e_sh[l]);
    float s_c = 0.f;
    float acc0 = 0, acc1 = 0, acc2 = 0, acc3 = 0;
    for (int l = 0; l < 32; ++l) {
        float p = expf(e_sh[l] - m_c);
        s_c += p;
        const float* row = enc + (size_t)(base + l) * HDIM;
        acc0 += p * row[t];
        acc1 += p * row[t + 256];
        acc2 += p * row[t + 512];
        acc3 += p * row[t + 768];
    }
    float* pp = part + (size_t)b * HDIM;
    pp[t] = acc0; pp[t + 256] = acc1; pp[t + 512] = acc2; pp[t + 768] = acc3;
    if (t == 0) { pm_a[b] = m_c; ps_a[b] = s_c; }
}

// ---------------------------------------------------------------------------
// 3. Combine 64 chunks per direction with rescaling -> concat attn slots.
__global__ void attn_combine_kernel(const float* __restrict__ part,
                                    const float* __restrict__ pm_a,
                                    const float* __restrict__ ps_a,
                                    float* __restrict__ concat) {
    int idx = blockIdx.x * 256 + threadIdx.x;   // 8 blocks -> 0..2047
    int d = idx >> 10, h = idx & 1023;
    float M = -1e30f;
#pragma unroll 8
    for (int c = 0; c < 64; ++c) M = fmaxf(M, pm_a[d * 64 + c]);
    float S = 0.f, acc = 0.f;
#pragma unroll 8
    for (int c = 0; c < 64; ++c) {
        int cb = d * 64 + c;
        float w = expf(pm_a[cb] - M);
        S += ps_a[cb] * w;
        acc += part[(size_t)cb * HDIM + h] * w;
    }
    concat[d * 2048 + h] = acc / S;
}

// ---------------------------------------------------------------------------
// 4. logits[v] = concat . W_out[v] + b_out[v].
//    BALANCED PERSISTENT GRID: 2048 blocks (one full residency wave),
//    each wave owns a contiguous run of ~6 vocab rows (~98 KB stream).
//    Eliminates the ~1-block-latency dispatch drain tail of a 12565-block
//    launch. Per-row inner body identical to the proven round-5 pattern.
__global__ void logits_kernel(const float* __restrict__ W_out,
                              const float* __restrict__ b_out,
                              const float* __restrict__ concat,
                              float* __restrict__ logits) {
    int wave = threadIdx.x >> 6, lane = threadIdx.x & 63;
    int gw = blockIdx.x * 4 + wave;             // 0..8191
    int v_beg = (int)(((long)gw * VOCAB) >> 13);        // gw*VOCAB/8192
    int v_end = (int)(((long)(gw + 1) * VOCAB) >> 13);
    for (int v = v_beg; v < v_end; ++v) {
        const float* w = W_out + (size_t)v * 4096;
        float acc = 0.f;
#pragma unroll
        for (int p = 0; p < 16; ++p) {
            int o = p * 256 + lane * 4;
            f4 a = __builtin_nontemporal_load((const f4*)(w + o));
            float4 b = *(const float4*)(concat + o);
            acc += a.x * b.x + a.y * b.y + a.z * b.z + a.w * b.w;
        }
        acc = wave_sum(acc);
        if (lane == 0) logits[v] = acc + b_out[v];
    }
}

// ---------------------------------------------------------------------------
// 5. per-block online log-sum-exp partials over logits. grid=128, block=256.
__global__ void lse_partial_kernel(const float* __restrict__ logits,
                                   float* __restrict__ pm,
                                   float* __restrict__ ps) {
    __shared__ float rm[4], rs[4];
    int tid = blockIdx.x * 256 + threadIdx.x;
    float m = -1e30f, s = 0.f;
    for (int v = tid; v < VOCAB; v += 128 * 256) lse_combine(m, s, logits[v], 1.f);
    int lane = threadIdx.x & 63, wave = threadIdx.x >> 6;
#pragma unroll
    for (int off = 32; off; off >>= 1) {
        float m2 = __shfl_down(m, off, 64);
        float s2 = __shfl_down(s, off, 64);
        lse_combine(m, s, m2, s2);
    }
    if (lane == 0) { rm[wave] = m; rs[wave] = s; }
    __syncthreads();
    if (threadIdx.x == 0) {
        float fm = rm[0], fs = rs[0];
        for (int w = 1; w < 4; ++w) lse_combine(fm, fs, rm[w], rs[w]);
        pm[blockIdx.x] = fm;
        ps[blockIdx.x] = fs;
    }
}

// ---------------------------------------------------------------------------
// 6. out[v] = logits[v] - M, M recomputed per block from 128 partials.
__global__ void out_kernel(const float* __restrict__ logits,
                           const float* __restrict__ pm,
                           const float* __restrict__ ps,
                           float* __restrict__ out) {
    __shared__ float rm[2], rs[2], Msh;
    int t = threadIdx.x, lane = t & 63, wave = t >> 6;
    float m = -1e30f, s = 0.f;
    if (t < 128) { m = pm[t]; s = ps[t]; }
#pragma unroll
    for (int off = 32; off; off >>= 1) {
        float m2 = __shfl_down(m, off, 64);
        float s2 = __shfl_down(s, off, 64);
        lse_combine(m, s, m2, s2);
    }
    if (lane == 0 && wave < 2) { rm[wave] = m; rs[wave] = s; }
    __syncthreads();
    if (t == 0) {
        float fm = rm[0], fs = rs[0];
        lse_combine(fm, fs, rm[1], rs[1]);
        Msh = fm + logf(fs);
    }
    __syncthreads();
    float M = Msh;
    int v = blockIdx.x * 256 + t;
    if (v < VOCAB) out[v] = logits[v] - M;
}

// ---------------------------------------------------------------------------
extern "C" void kernel_launch(void* const* d_in, const int* in_sizes, int n_in,
                              void* d_out, int out_size, void* d_ws, size_t ws_size,
                              hipStream_t stream) {
    const int*   tok    = (const int*)d_in[0];
    const float* hidden = (const float*)d_in[1];
    const float* enc    = (const float*)d_in[2];
    const float* emb    = (const float*)d_in[3];
    const float* W_ih   = (const float*)d_in[4];
    const float* W_hh   = (const float*)d_in[5];
    const float* b_ih   = (const float*)d_in[6];
    const float* b_hh   = (const float*)d_in[7];
    const float* W_out  = (const float*)d_in[8];
    const float* b_out  = (const float*)d_in[9];
    float* out = (float*)d_out;

    float* ws     = (float*)d_ws;
    float* concat = ws;                  // 4096
    float* pm_a   = ws + 4096;           // 128
    float* ps_a   = ws + 4224;           // 128
    float* pm     = ws + 4352;           // 128
    float* ps     = ws + 4480;           // 128
    float* part   = ws + 4608;           // 128*1024 = 131072
    float* logits = ws + 4608;           // aliases part (dead before K4)

    rnn_kernel<<<1024, 256, 0, stream>>>(tok, hidden, emb, W_ih, W_hh, b_ih, b_hh,
                                         concat, out + VOCAB);
    flash_attn_kernel<<<128, 256, 0, stream>>>(enc, concat, part, pm_a, ps_a);
    attn_combine_kernel<<<8, 256, 0, stream>>>(part, pm_a, ps_a, concat);
    logits_kernel<<<LOGIT_GRID, 256, 0, stream>>>(W_out, b_out, concat, logits);
    lse_partial_kernel<<<128, 256, 0, stream>>>(logits, pm, ps);
    out_kernel<<<(VOCAB + 255) / 256, 256, 0, stream>>>(logits, pm, ps, out);
}

// Round 9
// 158.088 us; speedup vs baseline: 1.1093x; 1.1093x over previous
//
#include <hip/hip_runtime.h>
#include <cmath>

#define HDIM 1024
#define LSEQ 2048
#define VOCAB 50257

typedef float f4 __attribute__((ext_vector_type(4)));

__device__ __forceinline__ float wave_sum(float v) {
#pragma unroll
    for (int off = 32; off; off >>= 1) v += __shfl_down(v, off, 64);
    return v;
}

__device__ __forceinline__ void lse_combine(float& m, float& s, float m2, float s2) {
    float nm = fmaxf(m, m2);
    s = s * expf(m - nm) + s2 * expf(m2 - nm);
    m = nm;
}

// ---------------------------------------------------------------------------
// 1. h = tanh(W_ih @ x + b_ih + W_hh @ h0 + b_hh).  split-K, 2 waves/row.
__global__ void rnn_kernel(const int* __restrict__ tok,
                           const float* __restrict__ hidden,
                           const float* __restrict__ emb,
                           const float* __restrict__ W_ih,
                           const float* __restrict__ W_hh,
                           const float* __restrict__ b_ih,
                           const float* __restrict__ b_hh,
                           float* __restrict__ concat,
                           float* __restrict__ out_h) {
    __shared__ float sh[4];
    int t = threadIdx.x;
    int wave = t >> 6, lane = t & 63;
    int subrow = wave >> 1;
    int half   = wave & 1;
    int row = blockIdx.x * 2 + subrow;
    int d = row >> 10, i = row & 1023;
    int tk = tok[0];
    int off = half * 512 + lane * 8;
    const float* x  = emb + (size_t)tk * HDIM + off;
    const float* h0 = hidden + d * HDIM + off;
    const float* wi = W_ih + (size_t)d * HDIM * HDIM + (size_t)i * HDIM + off;
    const float* wh = W_hh + (size_t)d * HDIM * HDIM + (size_t)i * HDIM + off;

    float4 a0 = *(const float4*)(wi);
    float4 a1 = *(const float4*)(wi + 4);
    float4 b0 = *(const float4*)(x);
    float4 b1 = *(const float4*)(x + 4);
    float4 c0 = *(const float4*)(wh);
    float4 c1 = *(const float4*)(wh + 4);
    float4 e0 = *(const float4*)(h0);
    float4 e1 = *(const float4*)(h0 + 4);
    float acc = a0.x * b0.x + a0.y * b0.y + a0.z * b0.z + a0.w * b0.w
              + a1.x * b1.x + a1.y * b1.y + a1.z * b1.z + a1.w * b1.w
              + c0.x * e0.x + c0.y * e0.y + c0.z * e0.z + c0.w * e0.w
              + c1.x * e1.x + c1.y * e1.y + c1.z * e1.z + c1.w * e1.w;
    acc = wave_sum(acc);
    if (lane == 0) sh[wave] = acc;
    __syncthreads();
    if ((t & 127) == 0) {
        float hv = tanhf(sh[subrow * 2] + sh[subrow * 2 + 1]
                         + b_ih[d * HDIM + i] + b_hh[d * HDIM + i]);
        concat[d * 2048 + 1024 + i] = hv;
        out_h[d * HDIM + i] = hv;
    }
}

// ---------------------------------------------------------------------------
// 2. Flash-style fused attention partials.
__global__ void flash_attn_kernel(const float* __restrict__ enc,
                                  const float* __restrict__ concat,
                                  float* __restrict__ part,
                                  float* __restrict__ pm_a,
                                  float* __restrict__ ps_a) {
    __shared__ float e_sh[32];
    int b = blockIdx.x;
    int d = b >> 6, c = b & 63;
    int t = threadIdx.x, wave = t >> 6, lane = t & 63;
    int base = c * 32;
    const float* h = concat + d * 2048 + 1024;

    for (int r = 0; r < 8; ++r) {
        int ll = wave * 8 + r;
        const float* er = enc + (size_t)(base + ll) * HDIM;
        float acc = 0.f;
#pragma unroll
        for (int p = 0; p < 4; ++p) {
            int o = p * 256 + lane * 4;
            float4 a = *(const float4*)(er + o);
            float4 bb = *(const float4*)(h + o);
            acc += a.x * bb.x + a.y * bb.y + a.z * bb.z + a.w * bb.w;
        }
        acc = wave_sum(acc);
        if (lane == 0) e_sh[ll] = acc;
    }
    __syncthreads();

    float m_c = -1e30f;
#pragma unroll
    for (int l = 0; l < 32; ++l) m_c = fmaxf(m_c, e_sh[l]);
    float s_c = 0.f;
    float acc0 = 0, acc1 = 0, acc2 = 0, acc3 = 0;
    for (int l = 0; l < 32; ++l) {
        float p = expf(e_sh[l] - m_c);
        s_c += p;
        const float* row = enc + (size_t)(base + l) * HDIM;
        acc0 += p * row[t];
        acc1 += p * row[t + 256];
        acc2 += p * row[t + 512];
        acc3 += p * row[t + 768];
    }
    float* pp = part + (size_t)b * HDIM;
    pp[t] = acc0; pp[t + 256] = acc1; pp[t + 512] = acc2; pp[t + 768] = acc3;
    if (t == 0) { pm_a[b] = m_c; ps_a[b] = s_c; }
}

// ---------------------------------------------------------------------------
// 3. Combine 64 chunks per direction with rescaling -> concat attn slots.
__global__ void attn_combine_kernel(const float* __restrict__ part,
                                    const float* __restrict__ pm_a,
                                    const float* __restrict__ ps_a,
                                    float* __restrict__ concat) {
    int idx = blockIdx.x * 256 + threadIdx.x;   // 8 blocks -> 0..2047
    int d = idx >> 10, h = idx & 1023;
    float M = -1e30f;
#pragma unroll 8
    for (int c = 0; c < 64; ++c) M = fmaxf(M, pm_a[d * 64 + c]);
    float S = 0.f, acc = 0.f;
#pragma unroll 8
    for (int c = 0; c < 64; ++c) {
        int cb = d * 64 + c;
        float w = expf(pm_a[cb] - M);
        S += ps_a[cb] * w;
        acc += part[(size_t)cb * HDIM + h] * w;
    }
    concat[d * 2048 + h] = acc / S;
}

// ---------------------------------------------------------------------------
// 4. logits[v] = concat . W_out[v] + b_out[v];  one wave per vocab row,
//    12565 blocks (proven-best streaming pattern — R5/R7).
//    ONLY change vs R5: concat staged in LDS once per block, so the VMEM
//    pipe issues exclusively W_out nt loads (concat reads move to LDS pipe).
__global__ void logits_kernel(const float* __restrict__ W_out,
                              const float* __restrict__ b_out,
                              const float* __restrict__ concat,
                              float* __restrict__ logits) {
    __shared__ float csh[4096];
    int t = threadIdx.x;
    int wave = t >> 6, lane = t & 63;
    // stage concat -> LDS (16 KB, coalesced float4, all 256 threads)
#pragma unroll
    for (int q = 0; q < 4; ++q) {
        int o = q * 1024 + t * 4;
        *(float4*)(csh + o) = *(const float4*)(concat + o);
    }
    __syncthreads();

    int v = blockIdx.x * 4 + wave;
    if (v >= VOCAB) return;
    const float* w = W_out + (size_t)v * 4096;
    float acc = 0.f;
#pragma unroll
    for (int p = 0; p < 16; ++p) {
        int o = p * 256 + lane * 4;
        f4 a = __builtin_nontemporal_load((const f4*)(w + o));
        float4 b = *(const float4*)(csh + o);
        acc += a.x * b.x + a.y * b.y + a.z * b.z + a.w * b.w;
    }
    acc = wave_sum(acc);
    if (lane == 0) logits[v] = acc + b_out[v];
}

// ---------------------------------------------------------------------------
// 5. per-block online log-sum-exp partials over logits. grid=128, block=256.
__global__ void lse_partial_kernel(const float* __restrict__ logits,
                                   float* __restrict__ pm,
                                   float* __restrict__ ps) {
    __shared__ float rm[4], rs[4];
    int tid = blockIdx.x * 256 + threadIdx.x;
    float m = -1e30f, s = 0.f;
    for (int v = tid; v < VOCAB; v += 128 * 256) lse_combine(m, s, logits[v], 1.f);
    int lane = threadIdx.x & 63, wave = threadIdx.x >> 6;
#pragma unroll
    for (int off = 32; off; off >>= 1) {
        float m2 = __shfl_down(m, off, 64);
        float s2 = __shfl_down(s, off, 64);
        lse_combine(m, s, m2, s2);
    }
    if (lane == 0) { rm[wave] = m; rs[wave] = s; }
    __syncthreads();
    if (threadIdx.x == 0) {
        float fm = rm[0], fs = rs[0];
        for (int w = 1; w < 4; ++w) lse_combine(fm, fs, rm[w], rs[w]);
        pm[blockIdx.x] = fm;
        ps[blockIdx.x] = fs;
    }
}

// ---------------------------------------------------------------------------
// 6. out[v] = logits[v] - M, M recomputed per block from 128 partials.
__global__ void out_kernel(const float* __restrict__ logits,
                           const float* __restrict__ pm,
                           const float* __restrict__ ps,
                           float* __restrict__ out) {
    __shared__ float rm[2], rs[2], Msh;
    int t = threadIdx.x, lane = t & 63, wave = t >> 6;
    float m = -1e30f, s = 0.f;
    if (t < 128) { m = pm[t]; s = ps[t]; }
#pragma unroll
    for (int off = 32; off; off >>= 1) {
        float m2 = __shfl_down(m, off, 64);
        float s2 = __shfl_down(s, off, 64);
        lse_combine(m, s, m2, s2);
    }
    if (lane == 0 && wave < 2) { rm[wave] = m; rs[wave] = s; }
    __syncthreads();
    if (t == 0) {
        float fm = rm[0], fs = rs[0];
        lse_combine(fm, fs, rm[1], rs[1]);
        Msh = fm + logf(fs);
    }
    __syncthreads();
    float M = Msh;
    int v = blockIdx.x * 256 + t;
    if (v < VOCAB) out[v] = logits[v] - M;
}

// ---------------------------------------------------------------------------
extern "C" void kernel_launch(void* const* d_in, const int* in_sizes, int n_in,
                              void* d_out, int out_size, void* d_ws, size_t ws_size,
                              hipStream_t stream) {
    const int*   tok    = (const int*)d_in[0];
    const float* hidden = (const float*)d_in[1];
    const float* enc    = (const float*)d_in[2];
    const float* emb    = (const float*)d_in[3];
    const float* W_ih   = (const float*)d_in[4];
    const float* W_hh   = (const float*)d_in[5];
    const float* b_ih   = (const float*)d_in[6];
    const float* b_hh   = (const float*)d_in[7];
    const float* W_out  = (const float*)d_in[8];
    const float* b_out  = (const float*)d_in[9];
    float* out = (float*)d_out;

    float* ws     = (float*)d_ws;
    float* concat = ws;                  // 4096
    float* pm_a   = ws + 4096;           // 128
    float* ps_a   = ws + 4224;           // 128
    float* pm     = ws + 4352;           // 128
    float* ps     = ws + 4480;           // 128
    float* part   = ws + 4608;           // 128*1024 = 131072
    float* logits = ws + 4608;           // aliases part (dead before K4)

    rnn_kernel<<<1024, 256, 0, stream>>>(tok, hidden, emb, W_ih, W_hh, b_ih, b_hh,
                                         concat, out + VOCAB);
    flash_attn_kernel<<<128, 256, 0, stream>>>(enc, concat, part, pm_a, ps_a);
    attn_combine_kernel<<<8, 256, 0, stream>>>(part, pm_a, ps_a, concat);
    logits_kernel<<<(VOCAB + 3) / 4, 256, 0, stream>>>(W_out, b_out, concat, logits);
    lse_partial_kernel<<<128, 256, 0, stream>>>(logits, pm, ps);
    out_kernel<<<(VOCAB + 255) / 256, 256, 0, stream>>>(logits, pm, ps, out);
}

// Round 10
// 154.255 us; speedup vs baseline: 1.1368x; 1.0248x over previous
//
#include <hip/hip_runtime.h>
#include <cmath>

#define HDIM 1024
#define LSEQ 2048
#define VOCAB 50257

typedef float f4 __attribute__((ext_vector_type(4)));

__device__ __forceinline__ float wave_sum(float v) {
#pragma unroll
    for (int off = 32; off; off >>= 1) v += __shfl_down(v, off, 64);
    return v;
}

__device__ __forceinline__ void lse_combine(float& m, float& s, float m2, float s2) {
    float nm = fmaxf(m, m2);
    s = s * expf(m - nm) + s2 * expf(m2 - nm);
    m = nm;
}

// ---------------------------------------------------------------------------
// 1. h = tanh(W_ih @ x + b_ih + W_hh @ h0 + b_hh);  one wave per output row.
__global__ void rnn_kernel(const int* __restrict__ tok,
                           const float* __restrict__ hidden,
                           const float* __restrict__ emb,
                           const float* __restrict__ W_ih,
                           const float* __restrict__ W_hh,
                           const float* __restrict__ b_ih,
                           const float* __restrict__ b_hh,
                           float* __restrict__ concat,
                           float* __restrict__ out_h) {
    int wave = threadIdx.x >> 6, lane = threadIdx.x & 63;
    int row = blockIdx.x * 4 + wave;            // 512 blocks * 4 waves = 2048
    int d = row >> 10, i = row & 1023;
    int t = tok[0];
    const float* x  = emb + (size_t)t * HDIM;
    const float* h0 = hidden + d * HDIM;
    const float* wi = W_ih + (size_t)d * HDIM * HDIM + (size_t)i * HDIM;
    const float* wh = W_hh + (size_t)d * HDIM * HDIM + (size_t)i * HDIM;
    float acc = 0.f;
#pragma unroll
    for (int p = 0; p < 4; ++p) {
        int o = p * 256 + lane * 4;
        float4 a = *(const float4*)(wi + o);
        float4 b = *(const float4*)(x + o);
        acc += a.x * b.x + a.y * b.y + a.z * b.z + a.w * b.w;
        float4 c = *(const float4*)(wh + o);
        float4 e = *(const float4*)(h0 + o);
        acc += c.x * e.x + c.y * e.y + c.z * e.z + c.w * e.w;
    }
    acc = wave_sum(acc);
    if (lane == 0) {
        float hv = tanhf(acc + b_ih[d * HDIM + i] + b_hh[d * HDIM + i]);
        concat[d * 2048 + 1024 + i] = hv;
        out_h[d * HDIM + i] = hv;
    }
}

// ---------------------------------------------------------------------------
// 2. Flash-style fused attention partials.
__global__ void flash_attn_kernel(const float* __restrict__ enc,
                                  const float* __restrict__ concat,
                                  float* __restrict__ part,
                                  float* __restrict__ pm_a,
                                  float* __restrict__ ps_a) {
    __shared__ float e_sh[32];
    int b = blockIdx.x;
    int d = b >> 6, c = b & 63;
    int t = threadIdx.x, wave = t >> 6, lane = t & 63;
    int base = c * 32;
    const float* h = concat + d * 2048 + 1024;

    for (int r = 0; r < 8; ++r) {
        int ll = wave * 8 + r;
        const float* er = enc + (size_t)(base + ll) * HDIM;
        float acc = 0.f;
#pragma unroll
        for (int p = 0; p < 4; ++p) {
            int o = p * 256 + lane * 4;
            float4 a = *(const float4*)(er + o);
            float4 bb = *(const float4*)(h + o);
            acc += a.x * bb.x + a.y * bb.y + a.z * bb.z + a.w * bb.w;
        }
        acc = wave_sum(acc);
        if (lane == 0) e_sh[ll] = acc;
    }
    __syncthreads();

    float m_c = -1e30f;
#pragma unroll
    for (int l = 0; l < 32; ++l) m_c = fmaxf(m_c, e_sh[l]);
    float s_c = 0.f;
    float acc0 = 0, acc1 = 0, acc2 = 0, acc3 = 0;
    for (int l = 0; l < 32; ++l) {
        float p = expf(e_sh[l] - m_c);
        s_c += p;
        const float* row = enc + (size_t)(base + l) * HDIM;
        acc0 += p * row[t];
        acc1 += p * row[t + 256];
        acc2 += p * row[t + 512];
        acc3 += p * row[t + 768];
    }
    float* pp = part + (size_t)b * HDIM;
    pp[t] = acc0; pp[t + 256] = acc1; pp[t + 512] = acc2; pp[t + 768] = acc3;
    if (t == 0) { pm_a[b] = m_c; ps_a[b] = s_c; }
}

// ---------------------------------------------------------------------------
// 3. Combine 64 chunks per direction with rescaling -> concat attn slots.
__global__ void attn_combine_kernel(const float* __restrict__ part,
                                    const float* __restrict__ pm_a,
                                    const float* __restrict__ ps_a,
                                    float* __restrict__ concat) {
    int idx = blockIdx.x * 256 + threadIdx.x;   // 8 blocks -> 0..2047
    int d = idx >> 10, h = idx & 1023;
    float M = -1e30f;
    for (int c = 0; c < 64; ++c) M = fmaxf(M, pm_a[d * 64 + c]);
    float S = 0.f, acc = 0.f;
    for (int c = 0; c < 64; ++c) {
        int cb = d * 64 + c;
        float w = expf(pm_a[cb] - M);
        S += ps_a[cb] * w;
        acc += part[(size_t)cb * HDIM + h] * w;
    }
    concat[d * 2048 + h] = acc / S;
}

// ---------------------------------------------------------------------------
// 4. logits[v] = concat . W_out[v] + b_out[v];  one wave per vocab row.
//    W_out read via NON-TEMPORAL loads (zero reuse, 823 MB stream);
//    concat loads stay cached (reused by every block).
//    PROVEN-BEST streaming pattern (R5: 154.7 us). Do not touch.
__global__ void logits_kernel(const float* __restrict__ W_out,
                              const float* __restrict__ b_out,
                              const float* __restrict__ concat,
                              float* __restrict__ logits) {
    int wave = threadIdx.x >> 6, lane = threadIdx.x & 63;
    int v = blockIdx.x * 4 + wave;
    if (v >= VOCAB) return;
    const float* w = W_out + (size_t)v * 4096;
    float acc = 0.f;
#pragma unroll
    for (int p = 0; p < 16; ++p) {
        int o = p * 256 + lane * 4;
        f4 a = __builtin_nontemporal_load((const f4*)(w + o));
        float4 b = *(const float4*)(concat + o);
        acc += a.x * b.x + a.y * b.y + a.z * b.z + a.w * b.w;
    }
    acc = wave_sum(acc);
    if (lane == 0) logits[v] = acc + b_out[v];
}

// ---------------------------------------------------------------------------
// 5. per-block online log-sum-exp partials over logits. grid=128, block=256.
__global__ void lse_partial_kernel(const float* __restrict__ logits,
                                   float* __restrict__ pm,
                                   float* __restrict__ ps) {
    __shared__ float rm[4], rs[4];
    int tid = blockIdx.x * 256 + threadIdx.x;
    float m = -1e30f, s = 0.f;
    for (int v = tid; v < VOCAB; v += 128 * 256) lse_combine(m, s, logits[v], 1.f);
    int lane = threadIdx.x & 63, wave = threadIdx.x >> 6;
#pragma unroll
    for (int off = 32; off; off >>= 1) {
        float m2 = __shfl_down(m, off, 64);
        float s2 = __shfl_down(s, off, 64);
        lse_combine(m, s, m2, s2);
    }
    if (lane == 0) { rm[wave] = m; rs[wave] = s; }
    __syncthreads();
    if (threadIdx.x == 0) {
        float fm = rm[0], fs = rs[0];
        for (int w = 1; w < 4; ++w) lse_combine(fm, fs, rm[w], rs[w]);
        pm[blockIdx.x] = fm;
        ps[blockIdx.x] = fs;
    }
}

// ---------------------------------------------------------------------------
// 6. out[v] = logits[v] - M, M recomputed per block from 128 partials.
__global__ void out_kernel(const float* __restrict__ logits,
                           const float* __restrict__ pm,
                           const float* __restrict__ ps,
                           float* __restrict__ out) {
    __shared__ float rm[2], rs[2], Msh;
    int t = threadIdx.x, lane = t & 63, wave = t >> 6;
    float m = -1e30f, s = 0.f;
    if (t < 128) { m = pm[t]; s = ps[t]; }
#pragma unroll
    for (int off = 32; off; off >>= 1) {
        float m2 = __shfl_down(m, off, 64);
        float s2 = __shfl_down(s, off, 64);
        lse_combine(m, s, m2, s2);
    }
    if (lane == 0 && wave < 2) { rm[wave] = m; rs[wave] = s; }
    __syncthreads();
    if (t == 0) {
        float fm = rm[0], fs = rs[0];
        lse_combine(fm, fs, rm[1], rs[1]);
        Msh = fm + logf(fs);
    }
    __syncthreads();
    float M = Msh;
    int v = blockIdx.x * 256 + t;
    if (v < VOCAB) out[v] = logits[v] - M;
}

// ---------------------------------------------------------------------------
extern "C" void kernel_launch(void* const* d_in, const int* in_sizes, int n_in,
                              void* d_out, int out_size, void* d_ws, size_t ws_size,
                              hipStream_t stream) {
    const int*   tok    = (const int*)d_in[0];
    const float* hidden = (const float*)d_in[1];
    const float* enc    = (const float*)d_in[2];
    const float* emb    = (const float*)d_in[3];
    const float* W_ih   = (const float*)d_in[4];
    const float* W_hh   = (const float*)d_in[5];
    const float* b_ih   = (const float*)d_in[6];
    const float* b_hh   = (const float*)d_in[7];
    const float* W_out  = (const float*)d_in[8];
    const float* b_out  = (const float*)d_in[9];
    float* out = (float*)d_out;

    float* ws     = (float*)d_ws;
    float* concat = ws;                  // 4096
    float* pm_a   = ws + 4096;           // 128
    float* ps_a   = ws + 4224;           // 128
    float* pm     = ws + 4352;           // 128
    float* ps     = ws + 4480;           // 128
    float* part   = ws + 4608;           // 128*1024 = 131072
    float* logits = ws + 4608;           // aliases part (dead before K4)
    // footprint ≈ 543 KB

    rnn_kernel<<<512, 256, 0, stream>>>(tok, hidden, emb, W_ih, W_hh, b_ih, b_hh,
                                        concat, out + VOCAB);
    flash_attn_kernel<<<128, 256, 0, stream>>>(enc, concat, part, pm_a, ps_a);
    attn_combine_kernel<<<8, 256, 0, stream>>>(part, pm_a, ps_a, concat);
    logits_kernel<<<(VOCAB + 3) / 4, 256, 0, stream>>>(W_out, b_out, concat, logits);
    lse_partial_kernel<<<128, 256, 0, stream>>>(logits, pm, ps);
    out_kernel<<<(VOCAB + 255) / 256, 256, 0, stream>>>(logits, pm, ps, out);
}